// Round 1
// baseline (57.502 us; speedup 1.0000x reference)
//
#include <hip/hip_runtime.h>
#include <math.h>

// Problem constants (setup_inputs: N=8192 rows, C=2048 classes)
#define NROWS 8192
#define NCLS  2048
#define P_POW 0.8f
#define LOG2E 1.44269504088896340736f
#define EPS   1e-6f

// ws layout:
//   [0, 8K)      int   counts[2048]
//   [8K, 16K)    float lc[2048]       (log2(count+1))
//   [16K, 48K)   float loss_arr[8192]

__global__ void zero_counts_k(int* __restrict__ counts) {
    int j = blockIdx.x * blockDim.x + threadIdx.x;
    if (j < NCLS) counts[j] = 0;
}

__global__ void hist_k(const int* __restrict__ labels, int* __restrict__ counts) {
    int i = blockIdx.x * blockDim.x + threadIdx.x;
    if (i < NROWS) atomicAdd(&counts[labels[i]], 1);
}

__global__ void prep_k(const int* __restrict__ counts, float* __restrict__ lc) {
    int j = blockIdx.x * blockDim.x + threadIdx.x;
    if (j < NCLS) lc[j] = log2f((float)(counts[j] + 1));
}

// One block (256 threads) per row. Each thread owns 8 columns (2 x float4).
__global__ __launch_bounds__(256) void row_loss_k(
        const float* __restrict__ logits,
        const int*   __restrict__ labels,
        const int*   __restrict__ counts,
        const float* __restrict__ lc,
        float*       __restrict__ loss_arr) {
    const int n = blockIdx.x;
    const int t = threadIdx.x;
    const int lane = t & 63, wid = t >> 6;

    const float4* row4 = reinterpret_cast<const float4*>(logits + (size_t)n * NCLS);
    float4 v0 = row4[t];         // cols 4t .. 4t+3
    float4 v1 = row4[t + 256];   // cols 1024+4t .. 1024+4t+3

    // ---- block max ----
    float m = fmaxf(fmaxf(fmaxf(v0.x, v0.y), fmaxf(v0.z, v0.w)),
                    fmaxf(fmaxf(v1.x, v1.y), fmaxf(v1.z, v1.w)));
    #pragma unroll
    for (int off = 32; off; off >>= 1) m = fmaxf(m, __shfl_xor(m, off, 64));
    __shared__ float redm[4];
    if (lane == 0) redm[wid] = m;
    __syncthreads();
    m = fmaxf(fmaxf(redm[0], redm[1]), fmaxf(redm[2], redm[3]));

    // ---- fused seesaw-weighted exp sum ----
    const int   y   = labels[n];       // uniform across block -> scalar load
    const int   cy  = counts[y];
    const float lcy = lc[y];

    float vals[8] = { v0.x, v0.y, v0.z, v0.w, v1.x, v1.y, v1.z, v1.w };
    const int j0 = 4 * t;

    float s = 0.0f;
    #pragma unroll
    for (int k = 0; k < 8; ++k) {
        int j = (k < 4) ? (j0 + k) : (1024 + j0 + (k - 4));
        int cj = counts[j];
        // s[y,j] = (cnt_y > cnt_j) ? (cnt_j/cnt_y)^0.8 : 1  -> additive log2 delta
        float delta = (cy > cj) ? P_POW * (lc[j] - lcy) : 0.0f;
        s += exp2f((vals[k] - m) * LOG2E + delta);
    }
    #pragma unroll
    for (int off = 32; off; off >>= 1) s += __shfl_xor(s, off, 64);
    __shared__ float reds[4];
    if (lane == 0) reds[wid] = s;
    __syncthreads();

    if (t == 0) {
        float denom = reds[0] + reds[1] + reds[2] + reds[3];
        float ey = exp2f((logits[(size_t)n * NCLS + y] - m) * LOG2E);
        float sigma = ey / (denom + EPS);
        loss_arr[n] = -logf(sigma + EPS);
    }
}

__global__ void finalize_k(const float* __restrict__ loss_arr, float* __restrict__ out) {
    int t = threadIdx.x;
    int lane = t & 63, wid = t >> 6;
    float s = 0.0f;
    for (int i = t; i < NROWS; i += 256) s += loss_arr[i];
    #pragma unroll
    for (int off = 32; off; off >>= 1) s += __shfl_xor(s, off, 64);
    __shared__ float red[4];
    if (lane == 0) red[wid] = s;
    __syncthreads();
    if (t == 0) out[0] = (red[0] + red[1] + red[2] + red[3]) / (float)NROWS;
}

extern "C" void kernel_launch(void* const* d_in, const int* in_sizes, int n_in,
                              void* d_out, int out_size, void* d_ws, size_t ws_size,
                              hipStream_t stream) {
    const float* logits = (const float*)d_in[0];
    const int*   labels = (const int*)d_in[1];
    float* out = (float*)d_out;

    char* ws = (char*)d_ws;
    int*   counts   = (int*)ws;                  // 2048 ints
    float* lc       = (float*)(ws + 8192);       // 2048 floats
    float* loss_arr = (float*)(ws + 16384);      // 8192 floats

    zero_counts_k<<<NCLS / 256, 256, 0, stream>>>(counts);
    hist_k<<<NROWS / 256, 256, 0, stream>>>(labels, counts);
    prep_k<<<NCLS / 256, 256, 0, stream>>>(counts, lc);
    row_loss_k<<<NROWS, 256, 0, stream>>>(logits, labels, counts, lc, loss_arr);
    finalize_k<<<1, 256, 0, stream>>>(loss_arr, out);
}

// Round 2
// 25.577 us; speedup vs baseline: 2.2482x; 2.2482x over previous
//
#include <hip/hip_runtime.h>
#include <math.h>

// Problem constants (setup_inputs: N=8192 rows, C=2048 classes)
#define NROWS 8192
#define NCLS  2048
#define LOG2E 1.44269504088896340736f
#define EPS   1e-6f

// ws layout:
//   [0, 8K)      float w[2048]        (0.8 * log2(count+1))
//   [8K, 40K)    float loss_arr[8192]

// ---------------------------------------------------------------------------
// Kernel 1: single-block LDS histogram of labels + table prep.
// w[j] = 0.8 * log2(count_j + 1).  Condition (cnt_y > cnt_j) <=> (w[j] < w[y])
// since log2 is strictly monotone on these small integers.
// ---------------------------------------------------------------------------
__global__ __launch_bounds__(256) void hist_prep_k(
        const int* __restrict__ labels, float* __restrict__ w) {
    __shared__ int cnt[NCLS];
    const int t = threadIdx.x;
    #pragma unroll
    for (int j = t; j < NCLS; j += 256) cnt[j] = 0;
    __syncthreads();
    const int4* lab4 = reinterpret_cast<const int4*>(labels);
    #pragma unroll
    for (int i = t; i < NROWS / 4; i += 256) {
        int4 L = lab4[i];
        atomicAdd(&cnt[L.x], 1);
        atomicAdd(&cnt[L.y], 1);
        atomicAdd(&cnt[L.z], 1);
        atomicAdd(&cnt[L.w], 1);
    }
    __syncthreads();
    #pragma unroll
    for (int j = t; j < NCLS; j += 256) w[j] = 0.8f * log2f((float)(cnt[j] + 1));
}

// ---------------------------------------------------------------------------
// Kernel 2: one wave (64 lanes) per row; 4 rows per 256-thread block.
// Each lane owns 32 columns as 8 float4 loads (all issued up-front for ILP).
// denom[n] = sum_j s[y_n,j] * e[n,j]   with s folded into the exponent:
//   s[y,j]*e[n,j] = exp2((v_j - m)*log2e + min(w[j]-w[y], 0))
// ---------------------------------------------------------------------------
__global__ __launch_bounds__(256) void row_loss_k(
        const float* __restrict__ logits,
        const int*   __restrict__ labels,
        const float* __restrict__ w,
        float*       __restrict__ loss_arr) {
    const int lane = threadIdx.x & 63;
    const int wid  = threadIdx.x >> 6;
    const int n    = blockIdx.x * 4 + wid;

    const float4* row4 = reinterpret_cast<const float4*>(logits + (size_t)n * NCLS);
    float4 v[8];
    #pragma unroll
    for (int k = 0; k < 8; ++k) v[k] = row4[k * 64 + lane];   // 8 loads in flight

    // ---- wave max (no barriers) ----
    float m = fmaxf(fmaxf(fmaxf(v[0].x, v[0].y), fmaxf(v[0].z, v[0].w)),
                    fmaxf(fmaxf(v[1].x, v[1].y), fmaxf(v[1].z, v[1].w)));
    #pragma unroll
    for (int k = 2; k < 8; ++k)
        m = fmaxf(m, fmaxf(fmaxf(v[k].x, v[k].y), fmaxf(v[k].z, v[k].w)));
    #pragma unroll
    for (int off = 32; off; off >>= 1) m = fmaxf(m, __shfl_xor(m, off, 64));

    const int   y    = labels[n];
    const float wy   = w[y];
    const float base = -m * LOG2E;

    const float4* w4 = reinterpret_cast<const float4*>(w);
    float s = 0.0f;
    #pragma unroll
    for (int k = 0; k < 8; ++k) {
        float4 wv = w4[k * 64 + lane];                         // L1-hit table load
        s += exp2f(fmaf(v[k].x, LOG2E, base) + fminf(wv.x - wy, 0.0f));
        s += exp2f(fmaf(v[k].y, LOG2E, base) + fminf(wv.y - wy, 0.0f));
        s += exp2f(fmaf(v[k].z, LOG2E, base) + fminf(wv.z - wy, 0.0f));
        s += exp2f(fmaf(v[k].w, LOG2E, base) + fminf(wv.w - wy, 0.0f));
    }
    #pragma unroll
    for (int off = 32; off; off >>= 1) s += __shfl_xor(s, off, 64);

    if (lane == 0) {
        float ey    = exp2f(fmaf(logits[(size_t)n * NCLS + y], LOG2E, base));
        float sigma = ey / (s + EPS);
        loss_arr[n] = -logf(sigma + EPS);
    }
}

// ---------------------------------------------------------------------------
// Kernel 3: deterministic mean over 8192 row losses (single block, float4).
// ---------------------------------------------------------------------------
__global__ __launch_bounds__(256) void finalize_k(
        const float* __restrict__ loss_arr, float* __restrict__ out) {
    const int t = threadIdx.x, lane = t & 63, wid = t >> 6;
    const float4* l4 = reinterpret_cast<const float4*>(loss_arr);
    float s = 0.0f;
    #pragma unroll
    for (int i = t; i < NROWS / 4; i += 256) {
        float4 v = l4[i];
        s += (v.x + v.y) + (v.z + v.w);
    }
    #pragma unroll
    for (int off = 32; off; off >>= 1) s += __shfl_xor(s, off, 64);
    __shared__ float red[4];
    if (lane == 0) red[wid] = s;
    __syncthreads();
    if (t == 0) out[0] = (red[0] + red[1] + red[2] + red[3]) / (float)NROWS;
}

extern "C" void kernel_launch(void* const* d_in, const int* in_sizes, int n_in,
                              void* d_out, int out_size, void* d_ws, size_t ws_size,
                              hipStream_t stream) {
    const float* logits = (const float*)d_in[0];
    const int*   labels = (const int*)d_in[1];
    float* out = (float*)d_out;

    char*  ws       = (char*)d_ws;
    float* w        = (float*)ws;               // 2048 floats
    float* loss_arr = (float*)(ws + 8192);      // 8192 floats

    hist_prep_k<<<1, 256, 0, stream>>>(labels, w);
    row_loss_k<<<NROWS / 4, 256, 0, stream>>>(logits, labels, w, loss_arr);
    finalize_k<<<1, 256, 0, stream>>>(loss_arr, out);
}

// Round 3
// 20.324 us; speedup vs baseline: 2.8292x; 1.2584x over previous
//
#include <hip/hip_runtime.h>
#include <math.h>

// N=8192 rows, C=2048 classes
#define NROWS 8192
#define NCLS  2048
#define NBLK  1024              // each block: full redundant histogram + 8 rows
#define LOG2E 1.44269504088896340736f
#define EPS   1e-6f

// ws: [0, 4K) float part[1024]

// ---------------------------------------------------------------------------
// Fused kernel: per-block redundant label histogram (labels = 32 KB, L2
// broadcast) + w-table + 8 rows of seesaw loss. Labels are issued BEFORE
// logits so vmcnt waits on labels don't drain the logits stream; hist-phase
// barriers are raw s_barrier + lgkmcnt(0) (no __syncthreads -> no vmcnt(0)
// drain), so the 64 MiB logits read overlaps the histogram work.
// ---------------------------------------------------------------------------
__global__ __launch_bounds__(256) void seesaw_rows_k(
        const float* __restrict__ logits,
        const int*   __restrict__ labels,
        float*       __restrict__ part) {
    __shared__ __align__(16) int   cnt[NCLS];
    __shared__ __align__(16) float w[NCLS];
    __shared__ float red[4];

    const int t    = threadIdx.x;
    const int lane = t & 63;
    const int wid  = t >> 6;

    // ---- labels first (8 x int4 per thread covers all 8192) ----
    const int4* lab4 = reinterpret_cast<const int4*>(labels);
    int4 L[8];
    #pragma unroll
    for (int i = 0; i < 8; ++i) L[i] = lab4[i * 256 + t];

    // ---- zero histogram ----
    #pragma unroll
    for (int j = t; j < NCLS; j += 256) cnt[j] = 0;
    asm volatile("s_waitcnt lgkmcnt(0)" ::: "memory");
    __builtin_amdgcn_s_barrier();
    asm volatile("" ::: "memory");

    // ---- redundant histogram ----
    #pragma unroll
    for (int i = 0; i < 8; ++i) {
        atomicAdd(&cnt[L[i].x], 1);
        atomicAdd(&cnt[L[i].y], 1);
        atomicAdd(&cnt[L[i].z], 1);
        atomicAdd(&cnt[L[i].w], 1);
    }
    asm volatile("s_waitcnt lgkmcnt(0)" ::: "memory");
    __builtin_amdgcn_s_barrier();
    asm volatile("" ::: "memory");

    // ---- w[j] = 0.8*log2(cnt_j+1); (cnt_y > cnt_j) <=> (w[j] < w[y]) ----
    #pragma unroll
    for (int j = t; j < NCLS; j += 256) w[j] = 0.8f * log2f((float)(cnt[j] + 1));
    asm volatile("s_waitcnt lgkmcnt(0)" ::: "memory");
    __builtin_amdgcn_s_barrier();
    asm volatile("" ::: "memory");

    const float4* w4 = reinterpret_cast<const float4*>(w);
    float myloss = 0.0f;   // lane 0 of each wave accumulates its 2 rows

    #pragma unroll
    for (int pass = 0; pass < 2; ++pass) {
        const int n = blockIdx.x * 8 + pass * 4 + wid;
        const float* rowp = logits + (size_t)n * NCLS;
        const float4* row4 = reinterpret_cast<const float4*>(rowp);

        const int y = labels[n];                 // uniform -> scalar load
        float4 v[8];
        #pragma unroll
        for (int k = 0; k < 8; ++k) v[k] = row4[k * 64 + lane];
        const float ylogit = rowp[y];            // uniform, L1/L2 hit

        // wave max
        float m = fmaxf(fmaxf(fmaxf(v[0].x, v[0].y), fmaxf(v[0].z, v[0].w)),
                        fmaxf(fmaxf(v[1].x, v[1].y), fmaxf(v[1].z, v[1].w)));
        #pragma unroll
        for (int k = 2; k < 8; ++k)
            m = fmaxf(m, fmaxf(fmaxf(v[k].x, v[k].y), fmaxf(v[k].z, v[k].w)));
        #pragma unroll
        for (int off = 32; off; off >>= 1) m = fmaxf(m, __shfl_xor(m, off, 64));

        const float wy   = w[y];
        const float base = -m * LOG2E;

        // denom = sum_j exp2((v_j - m)*log2e + min(w_j - w_y, 0))
        float s = 0.0f;
        #pragma unroll
        for (int k = 0; k < 8; ++k) {
            float4 wv = w4[k * 64 + lane];       // LDS ds_read_b128
            s += exp2f(fmaf(v[k].x, LOG2E, base) + fminf(wv.x - wy, 0.0f));
            s += exp2f(fmaf(v[k].y, LOG2E, base) + fminf(wv.y - wy, 0.0f));
            s += exp2f(fmaf(v[k].z, LOG2E, base) + fminf(wv.z - wy, 0.0f));
            s += exp2f(fmaf(v[k].w, LOG2E, base) + fminf(wv.w - wy, 0.0f));
        }
        #pragma unroll
        for (int off = 32; off; off >>= 1) s += __shfl_xor(s, off, 64);

        if (lane == 0) {
            float ey    = exp2f(fmaf(ylogit, LOG2E, base));
            float sigma = ey / (s + EPS);
            myloss += -logf(sigma + EPS);
        }
    }

    if (lane == 0) red[wid] = myloss;
    __syncthreads();
    if (t == 0) part[blockIdx.x] = (red[0] + red[1]) + (red[2] + red[3]);
}

// ---------------------------------------------------------------------------
// Deterministic mean over 1024 block partials.
// ---------------------------------------------------------------------------
__global__ __launch_bounds__(256) void finalize_k(
        const float* __restrict__ part, float* __restrict__ out) {
    const int t = threadIdx.x, lane = t & 63, wid = t >> 6;
    const float4* p4 = reinterpret_cast<const float4*>(part);
    float4 v = p4[t];                            // 256 x float4 = 1024
    float s = (v.x + v.y) + (v.z + v.w);
    #pragma unroll
    for (int off = 32; off; off >>= 1) s += __shfl_xor(s, off, 64);
    __shared__ float red[4];
    if (lane == 0) red[wid] = s;
    __syncthreads();
    if (t == 0) out[0] = (((red[0] + red[1]) + (red[2] + red[3]))) / (float)NROWS;
}

extern "C" void kernel_launch(void* const* d_in, const int* in_sizes, int n_in,
                              void* d_out, int out_size, void* d_ws, size_t ws_size,
                              hipStream_t stream) {
    const float* logits = (const float*)d_in[0];
    const int*   labels = (const int*)d_in[1];
    float* out  = (float*)d_out;
    float* part = (float*)d_ws;                  // 1024 floats

    seesaw_rows_k<<<NBLK, 256, 0, stream>>>(logits, labels, part);
    finalize_k<<<1, 256, 0, stream>>>(part, out);
}